// Round 14
// baseline (7835.644 us; speedup 1.0000x reference)
//
#include <hip/hip_runtime.h>
#include <hip/hip_bf16.h>
#include <stdint.h>

#define TT 1024
#define BB 32
#define DD 1024

typedef __attribute__((ext_vector_type(8))) short short8;
typedef __attribute__((ext_vector_type(4))) unsigned short ushort4v;
typedef __attribute__((ext_vector_type(4))) float floatx4;
typedef __attribute__((ext_vector_type(4))) unsigned uint4v;

static __device__ __forceinline__ unsigned short f2bf(float f){
  unsigned u = __float_as_uint(f);
  u += 0x7fffu + ((u >> 16) & 1u);   // RNE
  return (unsigned short)(u >> 16);
}
static __device__ __forceinline__ float bf2f(unsigned short s){
  return __uint_as_float(((unsigned)s) << 16);
}
static __device__ __forceinline__ float sigm(float x){
  return __fdividef(1.0f, 1.0f + __expf(-x));
}
static __device__ __forceinline__ float fast_tanh(float x){
  float e = __expf(2.0f * x);
  return 1.0f - __fdividef(2.0f, e + 1.0f);
}

// ---------------- workspace layout ----------------
// frag: [t][bh(2)][64KB block] = alpha fragments (first 32KB) + wx (second 32KB).
// h EXCHANGE (sentinel-gated, UNtagged, R13-proven):
//   h_{t+1} = plain bf16 [16 rows][1024 cols] (32KB) written over the DEAD alpha
//   half of block (t-1,bh) with relaxed agent ATOMIC 8B stores (-> MALL).
//   Producer wave drains (s_waitcnt vmcnt(0)) then bumps its per-wave SENTINEL.
//   Consumers poll 64 sentinels (1/lane) then PLAIN-load the data: fresh because
//   alpha halves are only ever read ATOMICALLY (no L1/L2 fill before the h
//   store), wx half is in different cache lines, no block is ever reused, and
//   cross-replay cache residue is value-identical (deterministic) hence benign.
#define WS_FRAG_BYTES (134217728ull)
#define WS_WCAT_OFF   (WS_FRAG_BYTES)
#define WS_WCAT_BYTES (4194304ull)
#define WS_H0_OFF     (WS_WCAT_OFF + WS_WCAT_BYTES)   // h0 bf16 [2][16][1024] = 64KB
#define WS_H1_OFF     (WS_H0_OFF + 65536ull)          // h1 bf16 [2][16][1024] = 64KB
#define WS_SENT_OFF   (WS_H1_OFF + 65536ull)          // 128 sentinels, 64B apart

__global__ void init_kernel(const float* __restrict__ Wa, const float* __restrict__ Wx,
                            const float* __restrict__ h0, float* __restrict__ hout0,
                            unsigned short* __restrict__ Wcat,
                            unsigned short* __restrict__ h0buf,
                            unsigned* __restrict__ sent)
{
  long i = (long)blockIdx.x * 256 + threadIdx.x;
  if (blockIdx.x == 0 && threadIdx.x < 128)
    __hip_atomic_store(&sent[threadIdx.x * 16], 0u, __ATOMIC_RELAXED, __HIP_MEMORY_SCOPE_AGENT);
  const long NW = 2048L * 1024L;
  for (long idx = i; idx < NW; idx += (long)gridDim.x * 256L){
    long r = idx >> 10, c = idx & 1023;
    float v = (r < 1024) ? Wa[r*1024 + c] : Wx[(r-1024)*1024 + c];
    Wcat[idx] = f2bf(v);
  }
  const long NH = 32L * 1024L;
  for (long idx = i; idx < NH; idx += (long)gridDim.x * 256L){
    float v = h0[idx];
    h0buf[idx] = f2bf(v);
    hout0[idx] = v;          // hout[0] = h0 (fp32)
  }
}

__global__ __launch_bounds__(256) void pre_gemm(
    const float* __restrict__ x, const unsigned short* __restrict__ Wcat,
    const float* __restrict__ b_alpha, const float* __restrict__ b_x,
    unsigned short* __restrict__ frag)
{
  __shared__ unsigned short A_lds[128*72];
  __shared__ unsigned short B_lds[128*72];
  const int tid = threadIdx.x;
  const int lane = tid & 63;
  const int w = tid >> 6;
  const int wm = w >> 1, wn = w & 1;
  const long m0 = (long)blockIdx.y * 128;
  const int n0 = blockIdx.x * 128;

  floatx4 acc[4][4];
#pragma unroll
  for (int i=0;i<4;++i)
#pragma unroll
    for (int j=0;j<4;++j) acc[i][j] = (floatx4){0.f,0.f,0.f,0.f};

  for (int kt=0; kt<16; ++kt){
    const int k0 = kt*64;
    __syncthreads();
#pragma unroll
    for (int rep=0; rep<4; ++rep){
      int flat = rep*2048 + tid*8;
      int r = flat >> 6, c = flat & 63;
      const float* src = &x[(m0 + r)*1024 + k0 + c];
      floatx4 f0 = *(const floatx4*)src;
      floatx4 f1 = *(const floatx4*)(src + 4);
      short8 v;
      v[0]=(short)f2bf(f0[0]); v[1]=(short)f2bf(f0[1]); v[2]=(short)f2bf(f0[2]); v[3]=(short)f2bf(f0[3]);
      v[4]=(short)f2bf(f1[0]); v[5]=(short)f2bf(f1[1]); v[6]=(short)f2bf(f1[2]); v[7]=(short)f2bf(f1[3]);
      *(short8*)&A_lds[r*72 + c] = v;
      short8 bv = *(const short8*)&Wcat[(long)(n0 + r)*1024 + k0 + c];
      *(short8*)&B_lds[r*72 + c] = bv;
    }
    __syncthreads();
#pragma unroll
    for (int kb=0; kb<2; ++kb){
      short8 a[4], b[4];
#pragma unroll
      for (int f=0; f<4; ++f)
        a[f] = *(const short8*)&A_lds[(wm*64 + f*16 + (lane&15))*72 + kb*32 + (lane>>4)*8];
#pragma unroll
      for (int f=0; f<4; ++f)
        b[f] = *(const short8*)&B_lds[(wn*64 + f*16 + (lane&15))*72 + kb*32 + (lane>>4)*8];
#pragma unroll
      for (int fm=0; fm<4; ++fm)
#pragma unroll
        for (int fn=0; fn<4; ++fn)
          acc[fm][fn] = __builtin_amdgcn_mfma_f32_16x16x32_bf16(a[fm], b[fn], acc[fm][fn], 0, 0, 0);
    }
  }

#pragma unroll
  for (int fm=0; fm<4; ++fm){
    const long mrow = m0 + wm*64 + fm*16;
    const int t  = (int)(mrow >> 5);
    const int bh = (int)((mrow >> 4) & 1);
#pragma unroll
    for (int fn=0; fn<4; ++fn){
      const int nf  = n0 + wn*64 + fn*16;
      const int nt  = nf >> 4;
      const int col = nf + (lane & 15);
      floatx4 v = acc[fm][fn];
      const float bias = (col < DD) ? b_alpha[col] : b_x[col - DD];
      ushort4v o;
#pragma unroll
      for (int i=0;i<4;++i) o[i] = f2bf(v[i] + bias);
      *(ushort4v*)&frag[((((long)t*2 + bh)*128 + nt)*64 + lane)*4] = o;
    }
  }
}

// ---------------- scan: sentinel-gated exchange, NO LDS, NO barriers in loop.
// Each wave: poll 64 sentinels -> plain-load its own A-fragments directly
// (4 waves/CU share via L1) -> MFMA vs Breg -> epilogue -> atomic stores ->
// vmcnt(0) -> per-wave sentinel. Waves fully self-paced.
__global__ __launch_bounds__(256, 1) void scan_kernel(
    const float* __restrict__ Wh, const float* __restrict__ h0,
    unsigned short* frag,
    const unsigned short* __restrict__ h0buf,
    unsigned short* h1buf,
    unsigned* sent)
{
  const int tid  = threadIdx.x;
  const int lane = tid & 63;
  const int w    = tid >> 6;
  const int bh   = blockIdx.x & 1;
  const int s    = blockIdx.x >> 1;
  const int base_r = s * 64;

  const int g8   = (lane >> 4) * 8;
  const int brow = w*16 + (lane & 15);

  // W_h slice row -> registers (fp32 load + convert, one-time)
  short8 Breg[32];
  {
    const float* Wr = &Wh[(long)(base_r + brow)*1024 + g8];
#pragma unroll
    for (int kb=0; kb<32; ++kb){
      floatx4 f0 = *(const floatx4*)&Wr[kb*32];
      floatx4 f1 = *(const floatx4*)&Wr[kb*32 + 4];
      short8 v;
      v[0]=(short)f2bf(f0[0]); v[1]=(short)f2bf(f0[1]); v[2]=(short)f2bf(f0[2]); v[3]=(short)f2bf(f0[3]);
      v[4]=(short)f2bf(f1[0]); v[5]=(short)f2bf(f1[1]); v[6]=(short)f2bf(f1[2]); v[7]=(short)f2bf(f1[3]);
      Breg[kb] = v;
    }
  }

  const int colf = base_r + w*16 + (lane & 15);
  const int nt_a = (base_r + w*16) >> 4;
  float hp[4];
#pragma unroll
  for (int i=0;i<4;++i){
    int gb = bh*16 + (lane>>4)*4 + i;
    hp[i] = h0[(long)gb*1024 + colf];
  }

  const int row_a = lane & 15;           // A-operand row for this lane

  unsigned* mysent = sent + (bh*64 + s*4 + w)*16;
  unsigned* gsent  = sent + bh*64*16;

  // alpha via ATOMIC 8B (keeps alpha-half lines out of L1/L2), wx via plain
  long fb = (((long)0*2 + bh)*128 + nt_a)*64 + lane;
  unsigned long long a0v = __hip_atomic_load((const unsigned long long*)&frag[fb*4],
                                             __ATOMIC_RELAXED, __HIP_MEMORY_SCOPE_AGENT);
  ushort4v al = __builtin_bit_cast(ushort4v, a0v);
  ushort4v wx = *(const ushort4v*)&frag[(fb + 64*64)*4];

  for (int t=0; t<TT; ++t){
    // ---- sentinel poll: lane L watches wave-sentinel L of this group
    if (t > 0){
      for (;;){
        unsigned v = __hip_atomic_load(&gsent[lane*16],
                                       __ATOMIC_RELAXED, __HIP_MEMORY_SCOPE_AGENT);
        if (__all(v >= (unsigned)t)) break;
      }
      asm volatile("" ::: "memory");     // pin data loads after poll
    }

    const unsigned short* hsrc =
        (t == 0) ? (h0buf + bh*16384) :
        (t == 1) ? (h1buf + bh*16384) :
                   (frag + ((long)(t-2)*2 + bh)*32768);
    const unsigned short* Arow = &hsrc[row_a*1024 + g8];

    // ---- direct per-wave A loads (plain dwordx4, L1-shared), software-pipelined
    short8 A0[8], A1[8];
#pragma unroll
    for (int j=0; j<8; ++j) A0[j] = *(const short8*)&Arow[j*32];

    floatx4 ac0 = (floatx4){0.f,0.f,0.f,0.f}, ac1 = ac0, ac2 = ac0, ac3 = ac0;
#pragma unroll
    for (int c=0; c<4; ++c){
      if (c < 3){
        if (c & 1){
#pragma unroll
          for (int j=0; j<8; ++j) A0[j] = *(const short8*)&Arow[((c+1)*8+j)*32];
        } else {
#pragma unroll
          for (int j=0; j<8; ++j) A1[j] = *(const short8*)&Arow[((c+1)*8+j)*32];
        }
      }
#pragma unroll
      for (int j=0; j<8; ++j){
        const int kb = c*8 + j;
        short8 afr = (c & 1) ? A1[j] : A0[j];
        if ((kb&3)==0) ac0 = __builtin_amdgcn_mfma_f32_16x16x32_bf16(afr, Breg[kb], ac0, 0, 0, 0);
        if ((kb&3)==1) ac1 = __builtin_amdgcn_mfma_f32_16x16x32_bf16(afr, Breg[kb], ac1, 0, 0, 0);
        if ((kb&3)==2) ac2 = __builtin_amdgcn_mfma_f32_16x16x32_bf16(afr, Breg[kb], ac2, 0, 0, 0);
        if ((kb&3)==3) ac3 = __builtin_amdgcn_mfma_f32_16x16x32_bf16(afr, Breg[kb], ac3, 0, 0, 0);
      }
    }
    floatx4 acc = (ac0 + ac1) + (ac2 + ac3);

    // ---- epilogue: h_{t+1}; pack 4 cols via 2x shfl_xor; atomic 8B stores
    unsigned short* hD = (t == 0) ? (h1buf + bh*16384)
                                  : (frag + ((long)(t-1)*2 + bh)*32768);
    const int c4 = colf & ~3;
    const bool st4 = ((lane & 3) == 0);
#pragma unroll
    for (int i=0;i<4;++i){
      float sv = acc[i] + bf2f(wx[i]);
      float v  = fast_tanh(sv);
      float aa = sigm(bf2f(al[i]));
      float hn = aa*hp[i] + (1.0f - aa)*v;
      hp[i] = hn;
      unsigned us = (unsigned)f2bf(hn);
      unsigned p01 = us | ((unsigned)__shfl_xor((int)us, 1, 64) << 16);
      unsigned p23 = (unsigned)__shfl_xor((int)p01, 2, 64);
      if (st4){
        unsigned long long pv = ((unsigned long long)p23 << 32) | p01;
        const int r = (lane>>4)*4 + i;
        __hip_atomic_store((unsigned long long*)&hD[r*1024 + c4], pv,
                           __ATOMIC_RELAXED, __HIP_MEMORY_SCOPE_AGENT);
      }
    }

    // ---- drain own stores, signal per-wave sentinel, prefetch alpha/wx
    if (t + 1 < TT){
      asm volatile("s_waitcnt vmcnt(0)" ::: "memory");  // h stores at MALL
      if (lane == 0)
        __hip_atomic_store(mysent, (unsigned)(t + 1),
                           __ATOMIC_RELAXED, __HIP_MEMORY_SCOPE_AGENT);
      fb = (((long)(t+1)*2 + bh)*128 + nt_a)*64 + lane;
      unsigned long long av = __hip_atomic_load((const unsigned long long*)&frag[fb*4],
                                                __ATOMIC_RELAXED, __HIP_MEMORY_SCOPE_AGENT);
      al = __builtin_bit_cast(ushort4v, av);
      wx = *(const ushort4v*)&frag[(fb + 64*64)*4];
    }
  }
}

// ---------------- expand bf16 h -> fp32 out/hout (off critical path)
__global__ __launch_bounds__(256) void out_writer(
    const unsigned short* __restrict__ frag,
    const unsigned short* __restrict__ h1buf,
    float* __restrict__ out, float* __restrict__ hout)
{
  const int t1 = blockIdx.z + 1;          // 1..1024
  const int bh = blockIdx.y;
  const int e  = (blockIdx.x*256 + threadIdx.x)*8;
  const int row = e >> 10, col = e & 1023;
  const unsigned short* src = (t1 == 1) ? (h1buf + bh*16384)
                                        : (frag + ((long)(t1-2)*2 + bh)*32768);
  short8 v = *(const short8*)&src[e];
  float o[8], hh[8];
#pragma unroll
  for (int j=0;j<8;++j){
    float h = bf2f((unsigned short)v[j]);
    float sg = sigm(h);
    hh[j] = h;
    o[j]  = h*h*sg;       // h * silu(h)
  }
  long ob = ((long)(t1-1)*BB + bh*16 + row)*DD + col;
  long hb = ((long)t1*BB + bh*16 + row)*DD + col;
  *(floatx4*)&out[ob]     = (floatx4){o[0],o[1],o[2],o[3]};
  *(floatx4*)&out[ob+4]   = (floatx4){o[4],o[5],o[6],o[7]};
  *(floatx4*)&hout[hb]    = (floatx4){hh[0],hh[1],hh[2],hh[3]};
  *(floatx4*)&hout[hb+4]  = (floatx4){hh[4],hh[5],hh[6],hh[7]};
}

extern "C" void kernel_launch(void* const* d_in, const int* in_sizes, int n_in,
                              void* d_out, int out_size, void* d_ws, size_t ws_size,
                              hipStream_t stream)
{
  const float* x  = (const float*)d_in[0];
  const float* h0 = (const float*)d_in[1];
  const float* Wa = (const float*)d_in[2];
  const float* ba = (const float*)d_in[3];
  const float* Wh = (const float*)d_in[4];
  const float* Wx = (const float*)d_in[5];
  const float* bx = (const float*)d_in[6];

  float* out  = (float*)d_out;
  float* hout = out + (long)TT*BB*DD;

  uint8_t* ws = (uint8_t*)d_ws;
  unsigned short* frag  = (unsigned short*)(ws);
  unsigned short* Wcat  = (unsigned short*)(ws + WS_WCAT_OFF);
  unsigned short* h0buf = (unsigned short*)(ws + WS_H0_OFF);
  unsigned short* h1buf = (unsigned short*)(ws + WS_H1_OFF);
  unsigned*       sent  = (unsigned*)      (ws + WS_SENT_OFF);

  init_kernel<<<8192, 256, 0, stream>>>(Wa, Wx, h0, hout, Wcat, h0buf, sent);
  pre_gemm<<<dim3(16, 256), 256, 0, stream>>>(x, Wcat, ba, bx, frag);
  scan_kernel<<<32, 256, 0, stream>>>(Wh, h0, frag, h0buf, h1buf, sent);
  out_writer<<<dim3(8, 2, 1024), 256, 0, stream>>>(frag, h1buf, out, hout);
}

// Round 15
// 5132.308 us; speedup vs baseline: 1.5267x; 1.5267x over previous
//
#include <hip/hip_runtime.h>
#include <hip/hip_bf16.h>
#include <stdint.h>

#define TT 1024
#define BB 32
#define DD 1024

typedef __attribute__((ext_vector_type(8))) short short8;
typedef __attribute__((ext_vector_type(4))) unsigned short ushort4v;
typedef __attribute__((ext_vector_type(4))) float floatx4;
typedef __attribute__((ext_vector_type(4))) unsigned uint4v;
typedef __attribute__((ext_vector_type(2))) unsigned uint2v;

static __device__ __forceinline__ unsigned short f2bf(float f){
  unsigned u = __float_as_uint(f);
  u += 0x7fffu + ((u >> 16) & 1u);   // RNE
  return (unsigned short)(u >> 16);
}
static __device__ __forceinline__ float bf2f(unsigned short s){
  return __uint_as_float(((unsigned)s) << 16);
}
static __device__ __forceinline__ float sigm(float x){
  return __fdividef(1.0f, 1.0f + __expf(-x));
}
static __device__ __forceinline__ float fast_tanh(float x){
  float e = __expf(2.0f * x);
  return 1.0f - __fdividef(2.0f, e + 1.0f);
}

// ---------------- workspace layout ----------------
// frag: [t][bh(2)][64KB block] = alpha fragments (32KB) + wx fragments (32KB).
// TAGGED h EXCHANGE (R10+R13 hybrid):
//   h_{t+1} = ull[16][512] granules over the WHOLE dead block (t-1,bh):
//   granule = { lo32 = bf16 col-pair, hi32 = ((t+2)<<16)|(t+2) }, written with
//   fire-and-forget relaxed agent ATOMIC 8B stores (no drain, no sentinel).
//   Consumer at step t+1 bulk PLAIN-loads block granules (coalesced,
//   L2-shareable), validates tags in-register; stale granules fall back to
//   per-granule ATOMIC reloads (bypass the now-cached stale line -> no
//   livelock; the block is never read again afterward). alpha/wx prefetch
//   uses ATOMIC loads so no future-h line is ever plain-cached (fast path
//   stays virgin). Tag collisions impossible: pre_gemm bf16 residue hi16s are
//   never 0x0001..0x0401 (denormals), poison 0xAAAAAAAA invalid, replay
//   residue is deterministic-identical hence benign.
#define WS_FRAG_BYTES (134217728ull)
#define WS_WCAT_OFF   (WS_FRAG_BYTES)
#define WS_WCAT_BYTES (4194304ull)
#define WS_H0T_OFF    (WS_WCAT_OFF + WS_WCAT_BYTES)   // tagged h0: 2*16*512 ull
#define WS_H1T_OFF    (WS_H0T_OFF + 131072ull)        // tagged h1

__global__ void init_kernel(const float* __restrict__ Wa, const float* __restrict__ Wx,
                            const float* __restrict__ h0, float* __restrict__ hout0,
                            unsigned short* __restrict__ Wcat,
                            unsigned long long* __restrict__ h0T,
                            unsigned long long* __restrict__ h1T)
{
  long i = (long)blockIdx.x * 256 + threadIdx.x;
  const long NW = 2048L * 1024L;
  for (long idx = i; idx < NW; idx += (long)gridDim.x * 256L){
    long r = idx >> 10, c = idx & 1023;
    float v = (r < 1024) ? Wa[r*1024 + c] : Wx[(r-1024)*1024 + c];
    Wcat[idx] = f2bf(v);
  }
  const long NG = 32L * 512L;
  for (long idx = i; idx < NG; idx += (long)gridDim.x * 256L){
    long row = idx >> 9, cp = idx & 511;
    float a = h0[row*1024 + 2*cp], b = h0[row*1024 + 2*cp + 1];
    unsigned hpair = ((unsigned)f2bf(b) << 16) | (unsigned)f2bf(a);
    h0T[idx] = ((unsigned long long)0x00010001u << 32) | hpair;   // tag = 1
    h1T[idx] = 0ull;                                              // invalid
  }
  const long NH = 32L * 1024L;
  for (long idx = i; idx < NH; idx += (long)gridDim.x * 256L)
    hout0[idx] = h0[idx];
}

__global__ __launch_bounds__(256) void pre_gemm(
    const float* __restrict__ x, const unsigned short* __restrict__ Wcat,
    const float* __restrict__ b_alpha, const float* __restrict__ b_x,
    unsigned short* __restrict__ frag)
{
  __shared__ unsigned short A_lds[128*72];
  __shared__ unsigned short B_lds[128*72];
  const int tid = threadIdx.x;
  const int lane = tid & 63;
  const int w = tid >> 6;
  const int wm = w >> 1, wn = w & 1;
  const long m0 = (long)blockIdx.y * 128;
  const int n0 = blockIdx.x * 128;

  floatx4 acc[4][4];
#pragma unroll
  for (int i=0;i<4;++i)
#pragma unroll
    for (int j=0;j<4;++j) acc[i][j] = (floatx4){0.f,0.f,0.f,0.f};

  for (int kt=0; kt<16; ++kt){
    const int k0 = kt*64;
    __syncthreads();
#pragma unroll
    for (int rep=0; rep<4; ++rep){
      int flat = rep*2048 + tid*8;
      int r = flat >> 6, c = flat & 63;
      const float* src = &x[(m0 + r)*1024 + k0 + c];
      floatx4 f0 = *(const floatx4*)src;
      floatx4 f1 = *(const floatx4*)(src + 4);
      short8 v;
      v[0]=(short)f2bf(f0[0]); v[1]=(short)f2bf(f0[1]); v[2]=(short)f2bf(f0[2]); v[3]=(short)f2bf(f0[3]);
      v[4]=(short)f2bf(f1[0]); v[5]=(short)f2bf(f1[1]); v[6]=(short)f2bf(f1[2]); v[7]=(short)f2bf(f1[3]);
      *(short8*)&A_lds[r*72 + c] = v;
      short8 bv = *(const short8*)&Wcat[(long)(n0 + r)*1024 + k0 + c];
      *(short8*)&B_lds[r*72 + c] = bv;
    }
    __syncthreads();
#pragma unroll
    for (int kb=0; kb<2; ++kb){
      short8 a[4], b[4];
#pragma unroll
      for (int f=0; f<4; ++f)
        a[f] = *(const short8*)&A_lds[(wm*64 + f*16 + (lane&15))*72 + kb*32 + (lane>>4)*8];
#pragma unroll
      for (int f=0; f<4; ++f)
        b[f] = *(const short8*)&B_lds[(wn*64 + f*16 + (lane&15))*72 + kb*32 + (lane>>4)*8];
#pragma unroll
      for (int fm=0; fm<4; ++fm)
#pragma unroll
        for (int fn=0; fn<4; ++fn)
          acc[fm][fn] = __builtin_amdgcn_mfma_f32_16x16x32_bf16(a[fm], b[fn], acc[fm][fn], 0, 0, 0);
    }
  }

#pragma unroll
  for (int fm=0; fm<4; ++fm){
    const long mrow = m0 + wm*64 + fm*16;
    const int t  = (int)(mrow >> 5);
    const int bh = (int)((mrow >> 4) & 1);
#pragma unroll
    for (int fn=0; fn<4; ++fn){
      const int nf  = n0 + wn*64 + fn*16;
      const int nt  = nf >> 4;
      const int col = nf + (lane & 15);
      floatx4 v = acc[fm][fn];
      const float bias = (col < DD) ? b_alpha[col] : b_x[col - DD];
      ushort4v o;
#pragma unroll
      for (int i=0;i<4;++i) o[i] = f2bf(v[i] + bias);
      *(ushort4v*)&frag[((((long)t*2 + bh)*128 + nt)*64 + lane)*4] = o;
    }
  }
}

// ---------------- scan: tagged exchange w/ plain-load fast path, W in regs
__global__ __launch_bounds__(256, 1) void scan_kernel(
    const float* __restrict__ Wh, const float* __restrict__ h0,
    unsigned short* frag,
    unsigned long long* h0T,
    unsigned long long* h1T)
{
  __shared__ unsigned h_lds[2][16*512];   // payload u32, 16B-unit XOR swizzle
  const int tid  = threadIdx.x;
  const int lane = tid & 63;
  const int w    = tid >> 6;
  const int bh   = blockIdx.x & 1;
  const int s    = blockIdx.x >> 1;
  const int base_r = s * 64;

  const int g8   = (lane >> 4) * 8;
  const int brow = w*16 + (lane & 15);

  // W_h slice row -> registers (fp32 load + convert, one-time)
  short8 Breg[32];
  {
    const float* Wr = &Wh[(long)(base_r + brow)*1024 + g8];
#pragma unroll
    for (int kb=0; kb<32; ++kb){
      floatx4 f0 = *(const floatx4*)&Wr[kb*32];
      floatx4 f1 = *(const floatx4*)&Wr[kb*32 + 4];
      short8 v;
      v[0]=(short)f2bf(f0[0]); v[1]=(short)f2bf(f0[1]); v[2]=(short)f2bf(f0[2]); v[3]=(short)f2bf(f0[3]);
      v[4]=(short)f2bf(f1[0]); v[5]=(short)f2bf(f1[1]); v[6]=(short)f2bf(f1[2]); v[7]=(short)f2bf(f1[3]);
      Breg[kb] = v;
    }
  }

  const int colf = base_r + w*16 + (lane & 15);
  const int nt_a = (base_r + w*16) >> 4;
  float hp[4];
#pragma unroll
  for (int i=0;i<4;++i){
    int gb = bh*16 + (lane>>4)*4 + i;
    hp[i] = h0[(long)gb*1024 + colf];
  }

  const int lrow = tid >> 4;             // staging row 0..15
  const int lc2  = (tid & 15) * 2;       // even granule base
  const int swl  = (lrow & 7) ^ ((lrow & 1) << 3);   // 16B-unit XOR (write)
  const int row_a = lane & 15;
  const int swr  = (row_a & 7) ^ ((row_a & 1) << 3); // 16B-unit XOR (read)

  // alpha AND wx via ATOMIC 8B loads: keeps every future-h line out of L1/L2
  long fb = (((long)0*2 + bh)*128 + nt_a)*64 + lane;
  unsigned long long a0v = __hip_atomic_load((const unsigned long long*)&frag[fb*4],
                                             __ATOMIC_RELAXED, __HIP_MEMORY_SCOPE_AGENT);
  unsigned long long w0v = __hip_atomic_load((const unsigned long long*)&frag[(fb + 64*64)*4],
                                             __ATOMIC_RELAXED, __HIP_MEMORY_SCOPE_AGENT);
  ushort4v al = __builtin_bit_cast(ushort4v, a0v);
  ushort4v wx = __builtin_bit_cast(ushort4v, w0v);

  const int ceven = colf & ~1;
  const bool iseven = ((lane & 1) == 0);

  for (int t=0; t<TT; ++t){
    const unsigned long long* hU =
        (t == 0) ? (h0T + bh*8192) :
        (t == 1) ? (h1T + bh*8192) :
                   (const unsigned long long*)(frag + ((long)(t-2)*2 + bh)*32768);
    const unsigned tt = ((unsigned)(t+1) << 16) | (unsigned)(t+1);
    unsigned* HB = h_lds[t & 1];

    // ---- fast path: bulk plain loads (coalesced), stage, tag-validate, fixup
#pragma unroll
    for (int b=0; b<2; ++b){
      uint4v L[8];
#pragma unroll
      for (int j=0; j<8; ++j)
        L[j] = *(const uint4v*)&hU[lrow*512 + lc2 + 32*(8*b + j)];
#pragma unroll
      for (int j=0; j<8; ++j){
        const int cp0 = lc2 + 32*(8*b + j);
        const int idx = lrow*512 + (((cp0 >> 2) ^ swl) << 2) + (cp0 & 3);
        *(uint2v*)&HB[idx] = (uint2v){L[j][0], L[j][2]};
        if (L[j][1] != tt){
          unsigned long long g;
          do { g = __hip_atomic_load(&hU[lrow*512 + cp0],
                                     __ATOMIC_RELAXED, __HIP_MEMORY_SCOPE_AGENT);
          } while ((unsigned)(g >> 32) != tt);
          HB[idx] = (unsigned)g;
        }
        if (L[j][3] != tt){
          unsigned long long g;
          do { g = __hip_atomic_load(&hU[lrow*512 + cp0 + 1],
                                     __ATOMIC_RELAXED, __HIP_MEMORY_SCOPE_AGENT);
          } while ((unsigned)(g >> 32) != tt);
          HB[idx + 1] = (unsigned)g;
        }
      }
    }
    __syncthreads();   // the ONLY barrier per step

    // ---- MFMA from LDS vs Breg
    floatx4 ac0 = (floatx4){0.f,0.f,0.f,0.f}, ac1 = ac0, ac2 = ac0, ac3 = ac0;
#pragma unroll
    for (int kb=0; kb<32; ++kb){
      const int u = kb*4 + (lane>>4);
      uint4v q = *(const uint4v*)&HB[row_a*512 + ((u ^ swr) << 2)];
      short8 afr = __builtin_bit_cast(short8, q);
      if ((kb&3)==0) ac0 = __builtin_amdgcn_mfma_f32_16x16x32_bf16(afr, Breg[kb], ac0, 0, 0, 0);
      if ((kb&3)==1) ac1 = __builtin_amdgcn_mfma_f32_16x16x32_bf16(afr, Breg[kb], ac1, 0, 0, 0);
      if ((kb&3)==2) ac2 = __builtin_amdgcn_mfma_f32_16x16x32_bf16(afr, Breg[kb], ac2, 0, 0, 0);
      if ((kb&3)==3) ac3 = __builtin_amdgcn_mfma_f32_16x16x32_bf16(afr, Breg[kb], ac3, 0, 0, 0);
    }
    floatx4 acc = (ac0 + ac1) + (ac2 + ac3);

    // ---- epilogue: tagged fire-and-forget stores (no drain, no sentinel)
    unsigned long long* hD =
        (t == 0) ? (h1T + bh*8192)
                 : (unsigned long long*)(frag + ((long)(t-1)*2 + bh)*32768);
    const unsigned ttn = ((unsigned)(t+2) << 16) | (unsigned)(t+2);
#pragma unroll
    for (int i=0;i<4;++i){
      float sv = acc[i] + bf2f(wx[i]);
      float v  = fast_tanh(sv);
      float aa = sigm(bf2f(al[i]));
      float hn = aa*hp[i] + (1.0f - aa)*v;
      hp[i] = hn;
      unsigned us    = (unsigned)f2bf(hn);
      unsigned other = (unsigned)__shfl_xor((int)us, 1, 64);
      if (iseven){
        unsigned hpair = (other << 16) | us;
        unsigned long long pv = ((unsigned long long)ttn << 32) | hpair;
        const int r = (lane>>4)*4 + i;
        __hip_atomic_store(&hD[r*512 + (ceven>>1)], pv,
                           __ATOMIC_RELAXED, __HIP_MEMORY_SCOPE_AGENT);
      }
    }

    // ---- prefetch next alpha/wx (atomic: keep future-h lines uncached)
    if (t + 1 < TT){
      fb = (((long)(t+1)*2 + bh)*128 + nt_a)*64 + lane;
      unsigned long long av = __hip_atomic_load((const unsigned long long*)&frag[fb*4],
                                                __ATOMIC_RELAXED, __HIP_MEMORY_SCOPE_AGENT);
      unsigned long long wv = __hip_atomic_load((const unsigned long long*)&frag[(fb + 64*64)*4],
                                                __ATOMIC_RELAXED, __HIP_MEMORY_SCOPE_AGENT);
      al = __builtin_bit_cast(ushort4v, av);
      wx = __builtin_bit_cast(ushort4v, wv);
    }
  }
}

// ---------------- expand tagged h -> fp32 out/hout (off critical path)
__global__ __launch_bounds__(256) void out_writer(
    const unsigned short* __restrict__ frag,
    const unsigned long long* __restrict__ h1T,
    float* __restrict__ out, float* __restrict__ hout)
{
  const int t1 = blockIdx.z + 1;
  const int bh = blockIdx.y;
  const int e  = (blockIdx.x*256 + threadIdx.x)*8;
  const int row = e >> 10, col = e & 1023;
  const unsigned long long* src =
      (t1 == 1) ? (h1T + bh*8192)
                : (const unsigned long long*)(frag + ((long)(t1-2)*2 + bh)*32768);
  const unsigned long long* p = &src[row*512 + (col>>1)];
  float o[8], hh[8];
#pragma unroll
  for (int g=0; g<4; ++g){
    unsigned hpair = (unsigned)p[g];
    float ha = bf2f((unsigned short)(hpair & 0xFFFFu));
    float hb = bf2f((unsigned short)(hpair >> 16));
    float sa = sigm(ha), sb = sigm(hb);
    hh[2*g] = ha;            hh[2*g+1] = hb;
    o[2*g]  = ha*ha*sa;      o[2*g+1]  = hb*hb*sb;
  }
  long ob = ((long)(t1-1)*BB + bh*16 + row)*DD + col;
  long hb = ((long)t1*BB + bh*16 + row)*DD + col;
  *(floatx4*)&out[ob]     = (floatx4){o[0],o[1],o[2],o[3]};
  *(floatx4*)&out[ob+4]   = (floatx4){o[4],o[5],o[6],o[7]};
  *(floatx4*)&hout[hb]    = (floatx4){hh[0],hh[1],hh[2],hh[3]};
  *(floatx4*)&hout[hb+4]  = (floatx4){hh[4],hh[5],hh[6],hh[7]};
}

extern "C" void kernel_launch(void* const* d_in, const int* in_sizes, int n_in,
                              void* d_out, int out_size, void* d_ws, size_t ws_size,
                              hipStream_t stream)
{
  const float* x  = (const float*)d_in[0];
  const float* h0 = (const float*)d_in[1];
  const float* Wa = (const float*)d_in[2];
  const float* ba = (const float*)d_in[3];
  const float* Wh = (const float*)d_in[4];
  const float* Wx = (const float*)d_in[5];
  const float* bx = (const float*)d_in[6];

  float* out  = (float*)d_out;
  float* hout = out + (long)TT*BB*DD;

  uint8_t* ws = (uint8_t*)d_ws;
  unsigned short*     frag = (unsigned short*)(ws);
  unsigned short*     Wcat = (unsigned short*)(ws + WS_WCAT_OFF);
  unsigned long long* h0T  = (unsigned long long*)(ws + WS_H0T_OFF);
  unsigned long long* h1T  = (unsigned long long*)(ws + WS_H1T_OFF);

  init_kernel<<<8192, 256, 0, stream>>>(Wa, Wx, h0, hout, Wcat, h0T, h1T);
  pre_gemm<<<dim3(16, 256), 256, 0, stream>>>(x, Wcat, ba, bx, frag);
  scan_kernel<<<32, 256, 0, stream>>>(Wh, h0, frag, h0T, h1T);
  out_writer<<<dim3(8, 2, 1024), 256, 0, stream>>>(frag, h1T, out, hout);
}